// Round 10
// baseline (72.699 us; speedup 1.0000x reference)
//
#include <hip/hip_runtime.h>
#include <hip/hip_bf16.h>
#include <math.h>

#define NROW 4096
#define DIM  512
#define M2   8192                     // 2N rows
#define SELF_EXP 7.3890560989306495f  // exp(1/T) = exp(2)
#define NTILE 64                      // M2 / 128
#define NBLK  (NTILE * (NTILE + 1) / 2)   // 2080 upper-triangle tiles (8*260)
#define NKS   8                       // 8 K-steps of 64 int8
#define LROW  528                     // LDS row stride: 512 + 16 pad (bank spread)
#define INV127SQ (1.0f / 16129.0f)    // 1/127^2 dequant scale

typedef __attribute__((ext_vector_type(4))) int   i32x4;    // 16 int8 / i32 C
typedef __attribute__((ext_vector_type(4))) float f32x4;

// ---------------------------------------------------------------------------
// Kernel 1: fused row-normalize (x,y -> int8 q = round(127*v_hat)) + positive-
// pair cosine partial (EXACT fp32 path) + rowsum zeroing + out zeroing.
// float4 loads, 2 rows per 256-thr block (R8-verified).
// ---------------------------------------------------------------------------
__global__ __launch_bounds__(256) void norm_pos_kernel(
    const float* __restrict__ x, const float* __restrict__ y,
    unsigned char* __restrict__ ns, float* __restrict__ pospart,
    float* __restrict__ rowsum, float* __restrict__ out)
{
    const int b = blockIdx.x;            // 0..2047
    const int t = threadIdx.x;           // 0..255
    const int h = t >> 7;                // row half within block
    const int u = t & 127;               // lane within row
    const int r = b * 2 + h;             // global row 0..4095

    const float4 a = ((const float4*)(x + (size_t)r * DIM))[u];
    const float4 c = ((const float4*)(y + (size_t)r * DIM))[u];
    float sx = a.x * a.x + a.y * a.y + a.z * a.z + a.w * a.w;
    float sy = c.x * c.x + c.y * c.y + c.z * c.z + c.w * c.w;
    float dt = a.x * c.x + a.y * c.y + a.z * c.z + a.w * c.w;
    #pragma unroll
    for (int o = 1; o < 64; o <<= 1) {
        sx += __shfl_xor(sx, o);
        sy += __shfl_xor(sy, o);
        dt += __shfl_xor(dt, o);
    }
    __shared__ float rd[4][3];
    const int w = t >> 6;                // wave 0..3 (waves 2h,2h+1 = row h)
    if ((t & 63) == 0) { rd[w][0] = sx; rd[w][1] = sy; rd[w][2] = dt; }
    __syncthreads();
    const float SX = rd[2 * h][0] + rd[2 * h + 1][0];
    const float SY = rd[2 * h][1] + rd[2 * h + 1][1];
    const float D  = rd[2 * h][2] + rd[2 * h + 1][2];
    const float rnx = rsqrtf(SX), rny = rsqrtf(SY);

    // unit-vector components in [-1,1] -> q in [-127,127], no clamp needed
    uchar4 qa, qc;
    qa.x = (unsigned char)(__float2int_rn(a.x * rnx * 127.f) & 0xff);
    qa.y = (unsigned char)(__float2int_rn(a.y * rnx * 127.f) & 0xff);
    qa.z = (unsigned char)(__float2int_rn(a.z * rnx * 127.f) & 0xff);
    qa.w = (unsigned char)(__float2int_rn(a.w * rnx * 127.f) & 0xff);
    qc.x = (unsigned char)(__float2int_rn(c.x * rny * 127.f) & 0xff);
    qc.y = (unsigned char)(__float2int_rn(c.y * rny * 127.f) & 0xff);
    qc.z = (unsigned char)(__float2int_rn(c.z * rny * 127.f) & 0xff);
    qc.w = (unsigned char)(__float2int_rn(c.w * rny * 127.f) & 0xff);
    ((uchar4*)(void*)(ns + (size_t)r * DIM))[u] = qa;
    ((uchar4*)(void*)(ns + (size_t)(r + NROW) * DIM))[u] = qc;

    if (u == 0) pospart[r] = D * rnx * rny;
    if (t < 4)  rowsum[4 * b + t] = 0.f;
    if (b == 0 && t == 0) out[0] = 0.f;
}

// ---------------------------------------------------------------------------
// Kernel 2: symmetric Gram (int8, mfma_i32_16x16x64_i8, exact int32 accum).
// R10 structure: FULL-K B-panel in LDS (128 x 512 int8, padded rows of 528 B
// for bank spread), staged ONCE per tile (reg-staged, plain loads/stores),
// then ALL 8 K-steps run BARRIER-FREE (LDS read-only). A fragments are read
// directly from global per step: ns is 4 MB (L2/L3-resident) and the av
// pattern (16 rows x 64 B contiguous per instr) uses cachelines fully.
// ONE __syncthreads per tile replaces R9's 8 barrier+vmcnt rounds.
// 66 KiB LDS -> 2 blocks/CU: inter-block overlap covers the stage drain
// (R1/R2 lesson: never 1 blk/CU). No k-permutation anywhere: A natural from
// global, B natural per-row (pad, not XOR) -> exact k alignment.
// Bank audit (528 = 512+16): slot = (row+g) mod 8 -> each 8-lane beat spans
// all 8 bank-quads, conflict-free; ds_write beats are contiguous-per-row.
// NOTE: __launch_bounds__(256,2) caps 256 VGPR >> ~180 worst case (no R3/R6
// spill mode); acc shape + epilogue byte-identical to R7-verified kernel.
// ---------------------------------------------------------------------------
__global__ __launch_bounds__(256, 2) void gram_rowsum_kernel(
    const unsigned char* __restrict__ ns, float* __restrict__ rowsum)
{
    __shared__ char lB[128 * LROW];    // 66 KiB padded B panel

    // XCD-chunked swizzle: 2080 % 8 == 0, each XCD gets 260 consecutive idx
    const int raw = blockIdx.x;
    const int idx = (raw & 7) * (NBLK / 8) + (raw >> 3);

    // decode upper-triangle tile index: idx = bj*(bj+1)/2 + bi, bi <= bj
    int bj = (int)floorf((sqrtf(8.0f * (float)idx + 1.0f) - 1.0f) * 0.5f);
    while ((bj + 1) * (bj + 2) / 2 <= idx) ++bj;
    while (bj * (bj + 1) / 2 > idx) --bj;
    const int bi = idx - bj * (bj + 1) / 2;

    const int t = threadIdx.x;
    const int lane = t & 63;
    const int l15  = lane & 15;
    const int wid  = t >> 6;
    const int wr = wid >> 1, wc = wid & 1;   // wave quadrant (64x64)
    const int g16 = (lane >> 4) * 16;        // 16-B k-slot within 64-B step

    const char* nsb = (const char*)ns;

    // ---- stage B panel (rows bj*128..+127, full K) into padded LDS -------
    #pragma unroll
    for (int l = 0; l < 16; ++l) {
        const int c   = l * 256 + t;          // 0..4095 16-B chunks
        const int row = c >> 5;               // 0..127 (32 chunks/row)
        const int col = (c & 31) * 16;        // 0..496
        const i32x4 v = *(const i32x4*)(
            nsb + (size_t)(bj * 128 + row) * DIM + col);
        *(i32x4*)(lB + row * LROW + col) = v;
    }

    i32x4 acc[4][4];
    #pragma unroll
    for (int m = 0; m < 4; ++m)
        #pragma unroll
        for (int n = 0; n < 4; ++n)
            acc[m][n] = (i32x4)0;

    // per-fragment base pointers (K-step folds into the load offset)
    const char* aBase[4];
    const char* bBase[4];
    #pragma unroll
    for (int m = 0; m < 4; ++m)
        aBase[m] = nsb + (size_t)(bi * 128 + wr * 64 + m * 16 + l15) * DIM + g16;
    #pragma unroll
    for (int n = 0; n < 4; ++n)
        bBase[n] = lB + (wc * 64 + n * 16 + l15) * LROW + g16;

    __syncthreads();   // B panel ready; LDS read-only from here on

    // ---- 8 K-steps, completely barrier-free ------------------------------
    #pragma unroll
    for (int ks = 0; ks < NKS; ++ks) {
        i32x4 av[4], bv[4];
        #pragma unroll
        for (int m = 0; m < 4; ++m)
            av[m] = *(const i32x4*)(aBase[m] + ks * 64);
        #pragma unroll
        for (int n = 0; n < 4; ++n)
            bv[n] = *(const i32x4*)(bBase[n] + ks * 64);
        #pragma unroll
        for (int m = 0; m < 4; ++m)
            #pragma unroll
            for (int n = 0; n < 4; ++n)
                acc[m][n] = __builtin_amdgcn_mfma_i32_16x16x64_i8(
                    av[m], bv[n], acc[m][n], 0, 0, 0);
    }

    // ---- epilogue: E = exp(2*acc/127^2); row sums; col sums off-diagonal --
    f32x4 e[4][4];
    #pragma unroll
    for (int m = 0; m < 4; ++m)
        #pragma unroll
        for (int n = 0; n < 4; ++n)
            #pragma unroll
            for (int r = 0; r < 4; ++r)
                e[m][n][r] = __expf((float)acc[m][n][r] * (2.0f * INV127SQ));

    // C/D layout (dtype-independent): row = m*16+(lane>>4)*4+reg ; col = n*16+(lane&15)
    #pragma unroll
    for (int m = 0; m < 4; ++m) {
        #pragma unroll
        for (int reg = 0; reg < 4; ++reg) {
            float p = e[m][0][reg] + e[m][1][reg] + e[m][2][reg] + e[m][3][reg];
            p += __shfl_xor(p, 1);
            p += __shfl_xor(p, 2);
            p += __shfl_xor(p, 4);
            p += __shfl_xor(p, 8);
            if (l15 == 0) {
                const int row = bi * 128 + wr * 64 + m * 16 + (lane >> 4) * 4 + reg;
                atomicAdd(&rowsum[row], p);
            }
        }
    }
    if (bi != bj) {
        #pragma unroll
        for (int n = 0; n < 4; ++n) {
            float p = 0.f;
            #pragma unroll
            for (int m = 0; m < 4; ++m)
                #pragma unroll
                for (int reg = 0; reg < 4; ++reg)
                    p += e[m][n][reg];
            p += __shfl_xor(p, 16);
            p += __shfl_xor(p, 32);
            if (lane < 16) {
                const int col = bj * 128 + wc * 64 + n * 16 + lane;
                atomicAdd(&rowsum[col], p);
            }
        }
    }
}

// ---------------------------------------------------------------------------
// Kernel 3: finalize -> loss, parallel (32 blocks, atomicAdd into out)
// ---------------------------------------------------------------------------
__global__ __launch_bounds__(256) void finalize_kernel(
    const float* __restrict__ rowsum, const float* __restrict__ pospart,
    float* __restrict__ out)
{
    const int b = blockIdx.x, t = threadIdx.x;
    float s  = logf(rowsum[b * 256 + t] - SELF_EXP);
    float pp = (t < 128) ? pospart[b * 128 + t] : 0.f;
    #pragma unroll
    for (int o = 1; o < 64; o <<= 1) {
        s  += __shfl_xor(s, o);
        pp += __shfl_xor(pp, o);
    }
    __shared__ float rd[8];
    if ((t & 63) == 0) { rd[t >> 6] = s; rd[4 + (t >> 6)] = pp; }
    __syncthreads();
    if (t == 0) {
        const float ts = rd[0] + rd[1] + rd[2] + rd[3];
        const float tp = rd[4] + rd[5] + rd[6] + rd[7];
        atomicAdd(out, (ts - 4.0f * tp) / (float)M2);
    }
}

// ---------------------------------------------------------------------------
extern "C" void kernel_launch(void* const* d_in, const int* in_sizes, int n_in,
                              void* d_out, int out_size, void* d_ws, size_t ws_size,
                              hipStream_t stream)
{
    const float* x = (const float*)d_in[0];
    const float* y = (const float*)d_in[1];
    float* out = (float*)d_out;

    char* ws = (char*)d_ws;
    unsigned char* ns = (unsigned char*)ws;                   // 4 MiB (int8)
    float* rowsum  = (float*)(ws + (size_t)4 * 1024 * 1024);  // 32 KiB
    float* pospart = rowsum + M2;                             // 16 KiB

    norm_pos_kernel<<<NROW / 2, 256, 0, stream>>>(x, y, ns, pospart, rowsum, out);

    gram_rowsum_kernel<<<NBLK, 256, 0, stream>>>(ns, rowsum);

    finalize_kernel<<<32, 256, 0, stream>>>(rowsum, pospart, out);
}

// Round 11
// 53.568 us; speedup vs baseline: 1.3571x; 1.3571x over previous
//
#include <hip/hip_runtime.h>
#include <hip/hip_bf16.h>
#include <math.h>

#define NROW 4096
#define DIM  512
#define M2   8192                     // 2N rows
#define SELF_EXP 7.3890560989306495f  // exp(1/T) = exp(2)
#define NTILE 64                      // M2 / 128
#define NBLK  (NTILE * (NTILE + 1) / 2)   // 2080 upper-triangle tiles (8*260)
#define BK    64                      // K-step (int8 elements) -> 64 B rows
#define NKS   (DIM / BK)              // 8 K-steps
#define LDS_TOTAL (5 * 16384)         // ring-5 x (A 8K + B 8K) = 80 KiB
#define INV127SQ (1.0f / 16129.0f)    // 1/127^2 dequant scale

typedef __attribute__((ext_vector_type(4))) int   i32x4;    // 16 int8 / i32 C
typedef __attribute__((ext_vector_type(4))) float f32x4;

// ---------------------------------------------------------------------------
// Kernel 1: fused row-normalize (x,y -> int8 q = round(127*v_hat)) + positive-
// pair cosine partial (EXACT fp32 path) + rowsum zeroing + out zeroing.
// float4 loads, 2 rows per 256-thr block (R8-verified).
// ---------------------------------------------------------------------------
__global__ __launch_bounds__(256) void norm_pos_kernel(
    const float* __restrict__ x, const float* __restrict__ y,
    unsigned char* __restrict__ ns, float* __restrict__ pospart,
    float* __restrict__ rowsum, float* __restrict__ out)
{
    const int b = blockIdx.x;            // 0..2047
    const int t = threadIdx.x;           // 0..255
    const int h = t >> 7;                // row half within block
    const int u = t & 127;               // lane within row
    const int r = b * 2 + h;             // global row 0..4095

    const float4 a = ((const float4*)(x + (size_t)r * DIM))[u];
    const float4 c = ((const float4*)(y + (size_t)r * DIM))[u];
    float sx = a.x * a.x + a.y * a.y + a.z * a.z + a.w * a.w;
    float sy = c.x * c.x + c.y * c.y + c.z * c.z + c.w * c.w;
    float dt = a.x * c.x + a.y * c.y + a.z * c.z + a.w * c.w;
    #pragma unroll
    for (int o = 1; o < 64; o <<= 1) {
        sx += __shfl_xor(sx, o);
        sy += __shfl_xor(sy, o);
        dt += __shfl_xor(dt, o);
    }
    __shared__ float rd[4][3];
    const int w = t >> 6;                // wave 0..3 (waves 2h,2h+1 = row h)
    if ((t & 63) == 0) { rd[w][0] = sx; rd[w][1] = sy; rd[w][2] = dt; }
    __syncthreads();
    const float SX = rd[2 * h][0] + rd[2 * h + 1][0];
    const float SY = rd[2 * h][1] + rd[2 * h + 1][1];
    const float D  = rd[2 * h][2] + rd[2 * h + 1][2];
    const float rnx = rsqrtf(SX), rny = rsqrtf(SY);

    // unit-vector components in [-1,1] -> q in [-127,127], no clamp needed
    uchar4 qa, qc;
    qa.x = (unsigned char)(__float2int_rn(a.x * rnx * 127.f) & 0xff);
    qa.y = (unsigned char)(__float2int_rn(a.y * rnx * 127.f) & 0xff);
    qa.z = (unsigned char)(__float2int_rn(a.z * rnx * 127.f) & 0xff);
    qa.w = (unsigned char)(__float2int_rn(a.w * rnx * 127.f) & 0xff);
    qc.x = (unsigned char)(__float2int_rn(c.x * rny * 127.f) & 0xff);
    qc.y = (unsigned char)(__float2int_rn(c.y * rny * 127.f) & 0xff);
    qc.z = (unsigned char)(__float2int_rn(c.z * rny * 127.f) & 0xff);
    qc.w = (unsigned char)(__float2int_rn(c.w * rny * 127.f) & 0xff);
    ((uchar4*)(void*)(ns + (size_t)r * DIM))[u] = qa;
    ((uchar4*)(void*)(ns + (size_t)(r + NROW) * DIM))[u] = qc;

    if (u == 0) pospart[r] = D * rnx * rny;
    if (t < 4)  rowsum[4 * b + t] = 0.f;
    if (b == 0 && t == 0) out[0] = 0.f;
}

// ---------------------------------------------------------------------------
// Kernel 2: symmetric Gram (int8, mfma_i32_16x16x64_i8, exact int32 accum).
// R11: RING-5 LDS (5 x 16 KiB = 80 KiB dynamic, 2 blk/CU) + ONE barrier per
// TWO K-steps (4 barrier rounds/tile vs R9's 8). Round r reads steps
// 2r,2r+1 (ring[s%5]); stages steps 2r+3,2r+4 into buffers last read at
// round r-1 (safe after this round's barrier). vmcnt stays COUNTED (4) until
// the tail: own stages of both steps-to-read are complete, one stays in
// flight. Stage slack 1-2 rounds (~800-1600 cyc) also covers HBM-miss.
// Per-buffer byte layout / swizzle / ds_read addresses / acc shape / epilogue
// byte-identical to the R9-verified kernel (0 conflicts, no spill).
// R10 lesson: NEVER read MFMA operands from global in the K-loop (latency-
// bound, 2x slower) - both operands stream through LDS.
// NOTE: R3: VGPR cap < acc -> spills; R6: mfma_scale reg shape -> spills.
// ---------------------------------------------------------------------------
__device__ __forceinline__ void stage_tiles(
    const char* nsb, char* buf, int bi, int bj, int koff, int t)
{
    #pragma unroll
    for (int l = 0; l < 4; ++l) {                 // exactly 4 loads/thread
        const int chunk = l * 256 + t;            // 0..1023 16B chunks
        const int half  = chunk >> 9;             // 0:A 1:B (wave-uniform)
        const int o     = (chunk & 511) * 16;     // byte off within 8 KiB tile
        const int row   = o >> 6;                 // 64 B per LDS row
        const int slot  = (o >> 4) & 3;
        const int src   = (slot ^ ((row >> 1) & 3)) << 4;  // inverse swizzle
        const int grow  = (half ? bj : bi) * 128 + row;
        const char* gsrc = nsb + (size_t)grow * DIM + koff + src;  // 512 B rows
        char* ldst = buf + half * 8192 + o;       // linear LDS dest
        __builtin_amdgcn_global_load_lds(
            (const __attribute__((address_space(1))) void*)gsrc,
            (__attribute__((address_space(3))) void*)ldst, 16, 0, 0);
    }
}

#define BARRIER() do { asm volatile("" ::: "memory");                          \
    __builtin_amdgcn_s_barrier(); asm volatile("" ::: "memory"); } while (0)
#define VMCNT(n) asm volatile("s_waitcnt vmcnt(" #n ")" ::: "memory")

__global__ __launch_bounds__(256, 2) void gram_rowsum_kernel(
    const unsigned char* __restrict__ ns, float* __restrict__ rowsum)
{
    extern __shared__ char smem[];     // 5 x 16384 ring

    // XCD-chunked swizzle: 2080 % 8 == 0, each XCD gets 260 consecutive idx
    const int raw = blockIdx.x;
    const int idx = (raw & 7) * (NBLK / 8) + (raw >> 3);

    // decode upper-triangle tile index: idx = bj*(bj+1)/2 + bi, bi <= bj
    int bj = (int)floorf((sqrtf(8.0f * (float)idx + 1.0f) - 1.0f) * 0.5f);
    while ((bj + 1) * (bj + 2) / 2 <= idx) ++bj;
    while (bj * (bj + 1) / 2 > idx) --bj;
    const int bi = idx - bj * (bj + 1) / 2;

    const int t = threadIdx.x;
    const int lane = t & 63;
    const int l15  = lane & 15;
    const int wid  = t >> 6;
    const int wr = wid >> 1, wc = wid & 1;   // wave quadrant (64x64)

    i32x4 acc[4][4];
    #pragma unroll
    for (int m = 0; m < 4; ++m)
        #pragma unroll
        for (int n = 0; n < 4; ++n)
            acc[m][n] = (i32x4)0;

    const char* nsb = (const char*)ns;
    const int kb2 = (lane >> 4) * 16;        // byte offset of 16B k-slot

    // prologue: stage K-steps 0,1,2 into ring[0..2]
    stage_tiles(nsb, smem + 0 * 16384, bi, bj, 0 * BK, t);
    stage_tiles(nsb, smem + 1 * 16384, bi, bj, 1 * BK, t);
    stage_tiles(nsb, smem + 2 * 16384, bi, bj, 2 * BK, t);

    #pragma unroll
    for (int r = 0; r < NKS / 2; ++r) {      // 4 barrier rounds, unrolled
        // own stages of steps 2r,2r+1 complete; newest stage may stay in flight
        if (r < 3) VMCNT(4); else VMCNT(0);
        BARRIER();   // all waves: stages done + round r-1 buffer reads done

        // stage steps 2r+3, 2r+4 into buffers read at round r-1
        if (r < 3) {
            const int s0 = 2 * r + 3;
            stage_tiles(nsb, smem + (s0 % 5) * 16384, bi, bj, s0 * BK, t);
            if (r < 2) {
                const int s1 = 2 * r + 4;
                stage_tiles(nsb, smem + (s1 % 5) * 16384, bi, bj, s1 * BK, t);
            }
        }
        __builtin_amdgcn_sched_barrier(0);   // keep stage issue above reads

        // compute steps 2r and 2r+1 (32 MFMA between barriers)
        #pragma unroll
        for (int h = 0; h < 2; ++h) {
            const int ks = 2 * r + h;
            const char* A = smem + (ks % 5) * 16384;
            const char* B = A + 8192;
            i32x4 av[4], bv[4];
            #pragma unroll
            for (int m = 0; m < 4; ++m) {
                const int row = wr * 64 + m * 16 + l15;
                const int sw  = ((row >> 1) & 3) << 4;
                av[m] = *(const i32x4*)(A + row * 64 + (kb2 ^ sw));
            }
            #pragma unroll
            for (int n = 0; n < 4; ++n) {
                const int row = wc * 64 + n * 16 + l15;
                const int sw  = ((row >> 1) & 3) << 4;
                bv[n] = *(const i32x4*)(B + row * 64 + (kb2 ^ sw));
            }
            #pragma unroll
            for (int m = 0; m < 4; ++m)
                #pragma unroll
                for (int n = 0; n < 4; ++n)
                    acc[m][n] = __builtin_amdgcn_mfma_i32_16x16x64_i8(
                        av[m], bv[n], acc[m][n], 0, 0, 0);
        }
    }

    // ---- epilogue: E = exp(2*acc/127^2); row sums; col sums off-diagonal --
    f32x4 e[4][4];
    #pragma unroll
    for (int m = 0; m < 4; ++m)
        #pragma unroll
        for (int n = 0; n < 4; ++n)
            #pragma unroll
            for (int r = 0; r < 4; ++r)
                e[m][n][r] = __expf((float)acc[m][n][r] * (2.0f * INV127SQ));

    // C/D layout (dtype-independent): row = m*16+(lane>>4)*4+reg ; col = n*16+(lane&15)
    #pragma unroll
    for (int m = 0; m < 4; ++m) {
        #pragma unroll
        for (int reg = 0; reg < 4; ++reg) {
            float p = e[m][0][reg] + e[m][1][reg] + e[m][2][reg] + e[m][3][reg];
            p += __shfl_xor(p, 1);
            p += __shfl_xor(p, 2);
            p += __shfl_xor(p, 4);
            p += __shfl_xor(p, 8);
            if (l15 == 0) {
                const int row = bi * 128 + wr * 64 + m * 16 + (lane >> 4) * 4 + reg;
                atomicAdd(&rowsum[row], p);
            }
        }
    }
    if (bi != bj) {
        #pragma unroll
        for (int n = 0; n < 4; ++n) {
            float p = 0.f;
            #pragma unroll
            for (int m = 0; m < 4; ++m)
                #pragma unroll
                for (int reg = 0; reg < 4; ++reg)
                    p += e[m][n][reg];
            p += __shfl_xor(p, 16);
            p += __shfl_xor(p, 32);
            if (lane < 16) {
                const int col = bj * 128 + wc * 64 + n * 16 + lane;
                atomicAdd(&rowsum[col], p);
            }
        }
    }
}

// ---------------------------------------------------------------------------
// Kernel 3: finalize -> loss, parallel (32 blocks, atomicAdd into out)
// ---------------------------------------------------------------------------
__global__ __launch_bounds__(256) void finalize_kernel(
    const float* __restrict__ rowsum, const float* __restrict__ pospart,
    float* __restrict__ out)
{
    const int b = blockIdx.x, t = threadIdx.x;
    float s  = logf(rowsum[b * 256 + t] - SELF_EXP);
    float pp = (t < 128) ? pospart[b * 128 + t] : 0.f;
    #pragma unroll
    for (int o = 1; o < 64; o <<= 1) {
        s  += __shfl_xor(s, o);
        pp += __shfl_xor(pp, o);
    }
    __shared__ float rd[8];
    if ((t & 63) == 0) { rd[t >> 6] = s; rd[4 + (t >> 6)] = pp; }
    __syncthreads();
    if (t == 0) {
        const float ts = rd[0] + rd[1] + rd[2] + rd[3];
        const float tp = rd[4] + rd[5] + rd[6] + rd[7];
        atomicAdd(out, (ts - 4.0f * tp) / (float)M2);
    }
}

// ---------------------------------------------------------------------------
extern "C" void kernel_launch(void* const* d_in, const int* in_sizes, int n_in,
                              void* d_out, int out_size, void* d_ws, size_t ws_size,
                              hipStream_t stream)
{
    const float* x = (const float*)d_in[0];
    const float* y = (const float*)d_in[1];
    float* out = (float*)d_out;

    char* ws = (char*)d_ws;
    unsigned char* ns = (unsigned char*)ws;                   // 4 MiB (int8)
    float* rowsum  = (float*)(ws + (size_t)4 * 1024 * 1024);  // 32 KiB
    float* pospart = rowsum + M2;                             // 16 KiB

    static bool attr_set = false;
    if (!attr_set) {
        (void)hipFuncSetAttribute((const void*)gram_rowsum_kernel,
                                  hipFuncAttributeMaxDynamicSharedMemorySize,
                                  LDS_TOTAL);
        attr_set = true;
    }

    norm_pos_kernel<<<NROW / 2, 256, 0, stream>>>(x, y, ns, pospart, rowsum, out);

    gram_rowsum_kernel<<<NBLK, 256, LDS_TOTAL, stream>>>(ns, rowsum);

    finalize_kernel<<<32, 256, 0, stream>>>(rowsum, pospart, out);
}

// Round 12
// 45.644 us; speedup vs baseline: 1.5927x; 1.1736x over previous
//
#include <hip/hip_runtime.h>
#include <hip/hip_bf16.h>
#include <math.h>

#define NROW 4096
#define DIM  512
#define M2   8192                     // 2N rows
#define SELF_EXP 7.3890560989306495f  // exp(1/T) = exp(2)
#define NTILE 64                      // M2 / 128
#define NBLK  (NTILE * (NTILE + 1) / 2)   // 2080 upper-triangle tiles (8*260)
#define BK    64                      // K-step (int8 elements) -> 64 B rows
#define NKS   (DIM / BK)              // 8 K-steps
#define INV127SQ (1.0f / 16129.0f)    // 1/127^2 dequant scale

typedef __attribute__((ext_vector_type(4))) int   i32x4;    // 16 int8 / i32 C
typedef __attribute__((ext_vector_type(4))) float f32x4;

// ---------------------------------------------------------------------------
// Kernel 1: fused row-normalize (x,y -> int8 q = round(127*v_hat)) + positive-
// pair cosine partial (EXACT fp32 path) + rowsum zeroing + out zeroing.
// float4 loads, 2 rows per 256-thr block (R8-verified, ~75% of HBM ceiling).
// ---------------------------------------------------------------------------
__global__ __launch_bounds__(256) void norm_pos_kernel(
    const float* __restrict__ x, const float* __restrict__ y,
    unsigned char* __restrict__ ns, float* __restrict__ pospart,
    float* __restrict__ rowsum, float* __restrict__ out)
{
    const int b = blockIdx.x;            // 0..2047
    const int t = threadIdx.x;           // 0..255
    const int h = t >> 7;                // row half within block
    const int u = t & 127;               // lane within row
    const int r = b * 2 + h;             // global row 0..4095

    const float4 a = ((const float4*)(x + (size_t)r * DIM))[u];
    const float4 c = ((const float4*)(y + (size_t)r * DIM))[u];
    float sx = a.x * a.x + a.y * a.y + a.z * a.z + a.w * a.w;
    float sy = c.x * c.x + c.y * c.y + c.z * c.z + c.w * c.w;
    float dt = a.x * c.x + a.y * c.y + a.z * c.z + a.w * c.w;
    #pragma unroll
    for (int o = 1; o < 64; o <<= 1) {
        sx += __shfl_xor(sx, o);
        sy += __shfl_xor(sy, o);
        dt += __shfl_xor(dt, o);
    }
    __shared__ float rd[4][3];
    const int w = t >> 6;                // wave 0..3 (waves 2h,2h+1 = row h)
    if ((t & 63) == 0) { rd[w][0] = sx; rd[w][1] = sy; rd[w][2] = dt; }
    __syncthreads();
    const float SX = rd[2 * h][0] + rd[2 * h + 1][0];
    const float SY = rd[2 * h][1] + rd[2 * h + 1][1];
    const float D  = rd[2 * h][2] + rd[2 * h + 1][2];
    const float rnx = rsqrtf(SX), rny = rsqrtf(SY);

    // unit-vector components in [-1,1] -> q in [-127,127], no clamp needed
    uchar4 qa, qc;
    qa.x = (unsigned char)(__float2int_rn(a.x * rnx * 127.f) & 0xff);
    qa.y = (unsigned char)(__float2int_rn(a.y * rnx * 127.f) & 0xff);
    qa.z = (unsigned char)(__float2int_rn(a.z * rnx * 127.f) & 0xff);
    qa.w = (unsigned char)(__float2int_rn(a.w * rnx * 127.f) & 0xff);
    qc.x = (unsigned char)(__float2int_rn(c.x * rny * 127.f) & 0xff);
    qc.y = (unsigned char)(__float2int_rn(c.y * rny * 127.f) & 0xff);
    qc.z = (unsigned char)(__float2int_rn(c.z * rny * 127.f) & 0xff);
    qc.w = (unsigned char)(__float2int_rn(c.w * rny * 127.f) & 0xff);
    ((uchar4*)(void*)(ns + (size_t)r * DIM))[u] = qa;
    ((uchar4*)(void*)(ns + (size_t)(r + NROW) * DIM))[u] = qc;

    if (u == 0) pospart[r] = D * rnx * rny;
    if (t < 4)  rowsum[4 * b + t] = 0.f;
    if (b == 0 && t == 0) out[0] = 0.f;
}

// ---------------------------------------------------------------------------
// Kernel 2: symmetric Gram (int8, mfma_i32_16x16x64_i8, exact int32 accum).
// R9-verified structure (best measured: ~31 us gram): RING-3 LDS (3 x 16 KiB,
// 3 blk/CU = 12 waves) + ONE merged barrier per K-step + counted vmcnt(4)
// (never drains hot loads until the tail). R12 adds T5 setprio(1) around the
// MFMA cluster: 3 independent blocks/CU sit at different phases, so a prio-1
// MFMA wave preempts co-resident blocks' staging waves (m191 mechanism).
// CONSTRAINT MAP (measured): acc 64 AGPR + working set -> total-reg cap 128
// -> max 4 waves/SIMD (R3: cap 48 spills; R6: mfma_scale shape spills);
// counted-vmcnt needs ring>=3 (R7 vs R9); occupancy >= 3 blk/CU beats
// barrier-halving at 2 blk/CU (R11); NEVER read MFMA operands from global
// in the K-loop (R10: latency-bound, 2x slower). Ring-2/4/5, BK=32/128,
// 2/4-phase templates all regress -> this is the constrained optimum.
// ---------------------------------------------------------------------------
__device__ __forceinline__ void stage_tiles(
    const char* nsb, char* buf, int bi, int bj, int koff, int t)
{
    #pragma unroll
    for (int l = 0; l < 4; ++l) {                 // exactly 4 loads/thread
        const int chunk = l * 256 + t;            // 0..1023 16B chunks
        const int half  = chunk >> 9;             // 0:A 1:B (wave-uniform)
        const int o     = (chunk & 511) * 16;     // byte off within 8 KiB tile
        const int row   = o >> 6;                 // 64 B per LDS row
        const int slot  = (o >> 4) & 3;
        const int src   = (slot ^ ((row >> 1) & 3)) << 4;  // inverse swizzle
        const int grow  = (half ? bj : bi) * 128 + row;
        const char* gsrc = nsb + (size_t)grow * DIM + koff + src;  // 512 B rows
        char* ldst = buf + half * 8192 + o;       // linear LDS dest
        __builtin_amdgcn_global_load_lds(
            (const __attribute__((address_space(1))) void*)gsrc,
            (__attribute__((address_space(3))) void*)ldst, 16, 0, 0);
    }
}

#define BARRIER() do { asm volatile("" ::: "memory");                          \
    __builtin_amdgcn_s_barrier(); asm volatile("" ::: "memory"); } while (0)
#define VMCNT(n) asm volatile("s_waitcnt vmcnt(" #n ")" ::: "memory")

__global__ __launch_bounds__(256, 3) void gram_rowsum_kernel(
    const unsigned char* __restrict__ ns, float* __restrict__ rowsum)
{
    __shared__ char ring[3][16384];    // 3 x (A 8 KiB + B 8 KiB)

    // XCD-chunked swizzle: 2080 % 8 == 0, each XCD gets 260 consecutive idx
    const int raw = blockIdx.x;
    const int idx = (raw & 7) * (NBLK / 8) + (raw >> 3);

    // decode upper-triangle tile index: idx = bj*(bj+1)/2 + bi, bi <= bj
    int bj = (int)floorf((sqrtf(8.0f * (float)idx + 1.0f) - 1.0f) * 0.5f);
    while ((bj + 1) * (bj + 2) / 2 <= idx) ++bj;
    while (bj * (bj + 1) / 2 > idx) --bj;
    const int bi = idx - bj * (bj + 1) / 2;

    const int t = threadIdx.x;
    const int lane = t & 63;
    const int l15  = lane & 15;
    const int wid  = t >> 6;
    const int wr = wid >> 1, wc = wid & 1;   // wave quadrant (64x64)

    i32x4 acc[4][4];
    #pragma unroll
    for (int m = 0; m < 4; ++m)
        #pragma unroll
        for (int n = 0; n < 4; ++n)
            acc[m][n] = (i32x4)0;

    const char* nsb = (const char*)ns;
    const int kb2 = (lane >> 4) * 16;        // byte offset of 16B k-slot

    // prologue: stage K-steps 0 and 1
    stage_tiles(nsb, ring[0], bi, bj, 0, t);
    stage_tiles(nsb, ring[1], bi, bj, BK, t);

    #pragma unroll
    for (int ks = 0; ks < NKS; ++ks) {       // fully unrolled: ks%3 is const
        // own stage(ks) complete (stage(ks+1) may stay in flight)
        if (ks < NKS - 1) VMCNT(4); else VMCNT(0);
        BARRIER();   // all waves: stage(ks) done AND buf[(ks-1)%3] reads done

        if (ks + 2 < NKS)
            stage_tiles(nsb, ring[(ks + 2) % 3], bi, bj, (ks + 2) * BK, t);
        __builtin_amdgcn_sched_barrier(0);   // keep stage issue above reads

        const char* A = ring[ks % 3];
        const char* B = ring[ks % 3] + 8192;
        i32x4 av[4], bv[4];
        #pragma unroll
        for (int m = 0; m < 4; ++m) {
            const int row = wr * 64 + m * 16 + l15;
            const int sw  = ((row >> 1) & 3) << 4;
            av[m] = *(const i32x4*)(A + row * 64 + (kb2 ^ sw));
        }
        #pragma unroll
        for (int n = 0; n < 4; ++n) {
            const int row = wc * 64 + n * 16 + l15;
            const int sw  = ((row >> 1) & 3) << 4;
            bv[n] = *(const i32x4*)(B + row * 64 + (kb2 ^ sw));
        }
        // K=64 per step: ONE i8 MFMA per 16x16 subtile; T5 prio boost so the
        // MFMA-phase block preempts co-resident blocks' staging waves
        __builtin_amdgcn_s_setprio(1);
        #pragma unroll
        for (int m = 0; m < 4; ++m)
            #pragma unroll
            for (int n = 0; n < 4; ++n)
                acc[m][n] = __builtin_amdgcn_mfma_i32_16x16x64_i8(
                    av[m], bv[n], acc[m][n], 0, 0, 0);
        __builtin_amdgcn_s_setprio(0);
    }

    // ---- epilogue: E = exp(2*acc/127^2); row sums; col sums off-diagonal --
    f32x4 e[4][4];
    #pragma unroll
    for (int m = 0; m < 4; ++m)
        #pragma unroll
        for (int n = 0; n < 4; ++n)
            #pragma unroll
            for (int r = 0; r < 4; ++r)
                e[m][n][r] = __expf((float)acc[m][n][r] * (2.0f * INV127SQ));

    // C/D layout (dtype-independent): row = m*16+(lane>>4)*4+reg ; col = n*16+(lane&15)
    #pragma unroll
    for (int m = 0; m < 4; ++m) {
        #pragma unroll
        for (int reg = 0; reg < 4; ++reg) {
            float p = e[m][0][reg] + e[m][1][reg] + e[m][2][reg] + e[m][3][reg];
            p += __shfl_xor(p, 1);
            p += __shfl_xor(p, 2);
            p += __shfl_xor(p, 4);
            p += __shfl_xor(p, 8);
            if (l15 == 0) {
                const int row = bi * 128 + wr * 64 + m * 16 + (lane >> 4) * 4 + reg;
                atomicAdd(&rowsum[row], p);
            }
        }
    }
    if (bi != bj) {
        #pragma unroll
        for (int n = 0; n < 4; ++n) {
            float p = 0.f;
            #pragma unroll
            for (int m = 0; m < 4; ++m)
                #pragma unroll
                for (int reg = 0; reg < 4; ++reg)
                    p += e[m][n][reg];
            p += __shfl_xor(p, 16);
            p += __shfl_xor(p, 32);
            if (lane < 16) {
                const int col = bj * 128 + wc * 64 + n * 16 + lane;
                atomicAdd(&rowsum[col], p);
            }
        }
    }
}

// ---------------------------------------------------------------------------
// Kernel 3: finalize -> loss, parallel (32 blocks, atomicAdd into out)
// ---------------------------------------------------------------------------
__global__ __launch_bounds__(256) void finalize_kernel(
    const float* __restrict__ rowsum, const float* __restrict__ pospart,
    float* __restrict__ out)
{
    const int b = blockIdx.x, t = threadIdx.x;
    float s  = logf(rowsum[b * 256 + t] - SELF_EXP);
    float pp = (t < 128) ? pospart[b * 128 + t] : 0.f;
    #pragma unroll
    for (int o = 1; o < 64; o <<= 1) {
        s  += __shfl_xor(s, o);
        pp += __shfl_xor(pp, o);
    }
    __shared__ float rd[8];
    if ((t & 63) == 0) { rd[t >> 6] = s; rd[4 + (t >> 6)] = pp; }
    __syncthreads();
    if (t == 0) {
        const float ts = rd[0] + rd[1] + rd[2] + rd[3];
        const float tp = rd[4] + rd[5] + rd[6] + rd[7];
        atomicAdd(out, (ts - 4.0f * tp) / (float)M2);
    }
}

// ---------------------------------------------------------------------------
extern "C" void kernel_launch(void* const* d_in, const int* in_sizes, int n_in,
                              void* d_out, int out_size, void* d_ws, size_t ws_size,
                              hipStream_t stream)
{
    const float* x = (const float*)d_in[0];
    const float* y = (const float*)d_in[1];
    float* out = (float*)d_out;

    char* ws = (char*)d_ws;
    unsigned char* ns = (unsigned char*)ws;                   // 4 MiB (int8)
    float* rowsum  = (float*)(ws + (size_t)4 * 1024 * 1024);  // 32 KiB
    float* pospart = rowsum + M2;                             // 16 KiB

    norm_pos_kernel<<<NROW / 2, 256, 0, stream>>>(x, y, ns, pospart, rowsum, out);

    gram_rowsum_kernel<<<NBLK, 256, 0, stream>>>(ns, rowsum);

    finalize_kernel<<<32, 256, 0, stream>>>(rowsum, pospart, out);
}